// Round 1
// 3742.916 us; speedup vs baseline: 1.0303x; 1.0303x over previous
//
#include <hip/hip_runtime.h>
#include <math.h>

// ---------------------------------------------------------------------------
// Problem constants (PatchTST-style transformer)
// ---------------------------------------------------------------------------
namespace {
constexpr int kB = 32, kT = 512, kC = 32, kD = 512, kDFF = 2048, kNL = 3;
constexpr int kP = 16, kStride = 8, kN = 64;
constexpr int kR = kB * kC;      // 1024 independent (b,c) series
constexpr int kM = kR * kN;      // 65536 tokens total
constexpr size_t kWbElems = (size_t)1536 * 512 + 512 * 512 + 2048 * 512 + 512 * 2048;
}

typedef unsigned short u16;
typedef __attribute__((ext_vector_type(8))) short short8;   // 8 bf16 (4 VGPRs)
typedef __attribute__((ext_vector_type(4))) float f32x4;    // MFMA accumulator

__device__ __forceinline__ float b2f(u16 u) {
    return __uint_as_float(((unsigned int)u) << 16);
}
__device__ __forceinline__ u16 f2b(float f) {
    unsigned int x = __float_as_uint(f);
    return (u16)((x + 0x7fffu + ((x >> 16) & 1u)) >> 16);
}

// async global->LDS, 16B per lane. lds ptr must be wave-uniform base.
__device__ __forceinline__ void async_copy16(const void* g, void* l) {
    __builtin_amdgcn_global_load_lds(
        (const __attribute__((address_space(1))) unsigned int*)g,
        (__attribute__((address_space(3))) unsigned int*)l, 16, 0, 0);
}

// ---------------------------------------------------------------------------
// Sentinel fill (workspace-too-small diagnostic)
// ---------------------------------------------------------------------------
__global__ void fill_kernel(float* __restrict__ p, float val, int n)
{
    int i = blockIdx.x * blockDim.x + threadIdx.x;
    if (i < n) p[i] = val;
}

// ---------------------------------------------------------------------------
// Instance-norm stats per (b,c)
// ---------------------------------------------------------------------------
__global__ __launch_bounds__(256) void instnorm_stats_kernel(
    const float* __restrict__ x, float* __restrict__ means, float* __restrict__ stdev)
{
    int b = blockIdx.x;
    int c = threadIdx.x & 31;
    int g = threadIdx.x >> 5;
    float s = 0.f, sq = 0.f;
    for (int t = g; t < kT; t += 8) {
        float v = x[(size_t)(b * kT + t) * kC + c];
        s += v; sq += v * v;
    }
    __shared__ float ss[8][32], ssq[8][32];
    ss[g][c] = s; ssq[g][c] = sq;
    __syncthreads();
    if (g == 0) {
        float S = 0.f, SQ = 0.f;
        for (int i = 0; i < 8; i++) { S += ss[i][c]; SQ += ssq[i][c]; }
        float m = S / kT;
        float var = SQ / kT - m * m;
        means[b * kC + c] = m;
        stdev[b * kC + c] = sqrtf(var + 1e-5f);
    }
}

// ---------------------------------------------------------------------------
// Patch embed (bf16 out)
// ---------------------------------------------------------------------------
__global__ __launch_bounds__(256) void patch_embed_kernel(
    const float* __restrict__ x, const float* __restrict__ Wval,
    const float* __restrict__ means, const float* __restrict__ stdev,
    u16* __restrict__ tok)
{
    int m = blockIdx.x;
    int r = m >> 6, n = m & 63;
    int b = r >> 5, c = r & 31;
    __shared__ float patch[kP];
    if (threadIdx.x < kP) {
        int t = n * kStride + threadIdx.x;
        if (t > kT - 1) t = kT - 1;
        patch[threadIdx.x] = (x[(size_t)(b * kT + t) * kC + c] - means[r]) / stdev[r];
    }
    __syncthreads();
    for (int d = threadIdx.x; d < kD; d += 256) {
        float acc = 0.f;
        #pragma unroll
        for (int p = 0; p < kP; p++) acc += patch[p] * Wval[p * kD + d];
        int j = d >> 1;
        float freq = expf(-(float)(2 * j) * (9.210340371976184f / (float)kD));
        float ang = (float)n * freq;
        float pe = (d & 1) ? cosf(ang) : sinf(ang);
        tok[(size_t)m * kD + d] = f2b(acc + pe);
    }
}

// ---------------------------------------------------------------------------
// Transpose + fp32->bf16 convert: out[n*ldo + k] = f2b(in[k*ldi + n])
// per z-slice: in += z*zin, out += z*zout.  grid (K/64, N/64, Z), 256 thr.
// ---------------------------------------------------------------------------
__global__ __launch_bounds__(256) void transpose_cvt_kernel(
    const float* __restrict__ in, u16* __restrict__ outp,
    int ldi, int ldo, int zin, int zout)
{
    __shared__ float tile[64][65];
    const float* ib = in + (size_t)blockIdx.z * zin;
    u16* ob = outp + (size_t)blockIdx.z * zout;
    int k0 = blockIdx.x * 64, n0 = blockIdx.y * 64;
    int tn = threadIdx.x & 63, tk0 = threadIdx.x >> 6;
    #pragma unroll
    for (int kk = tk0; kk < 64; kk += 4)
        tile[kk][tn] = ib[(size_t)(k0 + kk) * ldi + n0 + tn];
    __syncthreads();
    int wk = threadIdx.x & 63, wn0 = threadIdx.x >> 6;
    #pragma unroll
    for (int nn = wn0; nn < 64; nn += 4)
        ob[(size_t)(n0 + nn) * ldo + k0 + wk] = f2b(tile[wk][nn]);
}

// ---------------------------------------------------------------------------
// 256x256-tile, BK=64, 8-wave, 8-phase MFMA bf16 GEMM (T2+T3+T4+T5+T1).
//
// A: [M][lda] bf16 row-major.  B: [N][ldb] bf16 N-MAJOR (row n = output col).
// grid: (N/256, M/256, Z).  Z>1 = split-K (global k = z*K + kb), EPI 3 only.
// 512 threads = 8 waves (2M x 4N); per-wave output 128x64; acc[8][4] f32x4.
//
// LDS 128 KiB: {A0,B0,A1,B1} x 16K u16, linear [row][64] with chunk-XOR
// swizzle: 16B phys chunk p of row r holds logical chunk p ^ (r&7)
// (2-way max bank aliasing on ds_read_b128 -> free; global src pre-swizzled
// since global_load_lds writes base+lane*16 linearly).
//
// Schedule (race-free ledger, derived from the 8-phase template):
//   tile t -> buf[t&1]; iteration it computes tiles t0=2it (buf0, phases 1-4,
//   frags read ph1-2, reg-resident for ph3-4) and t1=2it+1 (buf1, phases 5-8).
//   Stage map: ph1 hB0(t1) ph2 hB1(t1) ph3 hA0(t2) ph4 hA1(t2)
//              ph5 hB0(t2) ph6 hB1(t2) ph7 hA0(t3) ph8 hA1(t3)
//   (overwrite of a buffer region always >=1 barrier after its last ds_read
//    has been drained by an MFMA lgkm wait; DS completes in-order.)
//   vmcnt(4) at ph4/ph8 drains exactly the next tile's 4 halves while leaving
//   2 half-tiles (4 loads) in flight.  Final iteration: no ph3-8 stages,
//   vmcnt(0) at ph4.
// EPI 0: qkv — dst/bias by 512-col group: C0/C1/C2, bias/auxb1/auxb2
// EPI 1: C0[r*ldc+c] += acc + (bias?bias[c]:0)       (bf16 rmw)
// EPI 2: C0[r*ldc+c]  = gelu_erf(acc + bias[c])
// EPI 3: atomicAdd(fout[((r>>5)*512+c)*32 + (r&31)], acc*stdev[r])
// ---------------------------------------------------------------------------
template<int EPI>
__global__ __launch_bounds__(512, 2) void gemm8(
    const u16* __restrict__ A, const u16* __restrict__ B,
    const float* __restrict__ bias, const float* __restrict__ auxb1,
    const float* __restrict__ auxb2,
    u16* __restrict__ C0, u16* __restrict__ C1, u16* __restrict__ C2,
    float* __restrict__ fout, const float* __restrict__ stdev,
    int K, int lda, int ldb, int ldc)
{
    __shared__ u16 sm[65536];          // 128 KiB
    u16* const bufA0 = sm;
    u16* const bufB0 = sm + 16384;
    u16* const bufA1 = sm + 32768;
    u16* const bufB1 = sm + 49152;

    const int tid  = threadIdx.x;
    const int lane = tid & 63;
    const int wave = tid >> 6;
    const int wm   = wave >> 2;        // 0..1
    const int wn   = wave & 3;         // 0..3

    // bijective XCD swizzle (m204) over the (x,y) grid plane
    const int nwg  = gridDim.x * gridDim.y;
    const int orig = blockIdx.y * gridDim.x + blockIdx.x;
    const int qq = nwg >> 3, rr = nwg & 7;
    const int xcd = orig & 7, loc = orig >> 3;
    const int wg  = (xcd < rr) ? (xcd * (qq + 1) + loc)
                               : (rr * (qq + 1) + (xcd - rr) * qq + loc);
    const int row0 = (wg / gridDim.x) * 256;
    const int col0 = (wg % gridDim.x) * 256;
    const size_t zoff = (size_t)blockIdx.z * K;

    // staging: one global_load_lds covers 64 rows (512 thr x 16B); the lane
    // fetches logical chunk (lane&7)^(lane>>3) so linear LDS ends up swizzled
    const int srow = (wave << 3) + (lane >> 3);          // 0..63
    const int scol = ((lane & 7) ^ (lane >> 3)) << 3;
    const u16* const Ag = A + (size_t)(row0 + srow) * lda + zoff + scol;
    const u16* const Bg = B + (size_t)(col0 + srow) * ldb + zoff + scol;
    const int lw = wave << 3;

#define STAGE_A(BUF, R0, T) do { \
        const u16* g_ = Ag + (size_t)(R0) * lda + (T) * 64; \
        u16* l_ = bufA##BUF + (((R0) + lw) << 6); \
        async_copy16(g_, l_); \
        async_copy16(g_ + (size_t)64 * lda, l_ + (64 << 6)); \
    } while (0)
#define STAGE_B(BUF, R0, T) do { \
        const u16* g_ = Bg + (size_t)(R0) * ldb + (T) * 64; \
        u16* l_ = bufB##BUF + (((R0) + lw) << 6); \
        async_copy16(g_, l_); \
        async_copy16(g_ + (size_t)64 * ldb, l_ + (64 << 6)); \
    } while (0)

    // fragment read offsets (u16 elements); phys chunk for kt=0 is
    // quad^(row&7) with row&7 == lane&7; kt=1 flips bit2 of the phys chunk
    const int fr = lane & 15;
    const int pc = (lane >> 4) ^ (lane & 7);
    const int a0 = ((wm << 7) + fr) * 64 + pc * 8;
    const int a1 = ((wm << 7) + fr) * 64 + (pc ^ 4) * 8;
    const int b0 = ((wn << 6) + fr) * 64 + pc * 8;
    const int b1 = ((wn << 6) + fr) * 64 + (pc ^ 4) * 8;

    short8 af[8][2], bfr[4][2];
    f32x4 acc[8][4];
    #pragma unroll
    for (int i = 0; i < 8; i++)
        #pragma unroll
        for (int j = 0; j < 4; j++)
            acc[i][j] = (f32x4){0.f, 0.f, 0.f, 0.f};

#define RD_A(BUF, MH) do { \
        _Pragma("unroll") \
        for (int mi_ = 0; mi_ < 4; mi_++) { \
            af[(MH)*4 + mi_][0] = *(const short8*)&bufA##BUF[a0 + (((MH)*4 + mi_) << 10)]; \
            af[(MH)*4 + mi_][1] = *(const short8*)&bufA##BUF[a1 + (((MH)*4 + mi_) << 10)]; \
        } \
    } while (0)
#define RD_B(BUF, NH) do { \
        _Pragma("unroll") \
        for (int ni_ = 0; ni_ < 2; ni_++) { \
            bfr[(NH)*2 + ni_][0] = *(const short8*)&bufB##BUF[b0 + (((NH)*2 + ni_) << 10)]; \
            bfr[(NH)*2 + ni_][1] = *(const short8*)&bufB##BUF[b1 + (((NH)*2 + ni_) << 10)]; \
        } \
    } while (0)
#define MFMA_Q(MH, NH) do { \
        __builtin_amdgcn_s_setprio(1); \
        _Pragma("unroll") \
        for (int mi_ = 0; mi_ < 4; mi_++) \
            _Pragma("unroll") \
            for (int ni_ = 0; ni_ < 2; ni_++) { \
                acc[(MH)*4 + mi_][(NH)*2 + ni_] = __builtin_amdgcn_mfma_f32_16x16x32_bf16( \
                    af[(MH)*4 + mi_][0], bfr[(NH)*2 + ni_][0], \
                    acc[(MH)*4 + mi_][(NH)*2 + ni_], 0, 0, 0); \
                acc[(MH)*4 + mi_][(NH)*2 + ni_] = __builtin_amdgcn_mfma_f32_16x16x32_bf16( \
                    af[(MH)*4 + mi_][1], bfr[(NH)*2 + ni_][1], \
                    acc[(MH)*4 + mi_][(NH)*2 + ni_], 0, 0, 0); \
            } \
        __builtin_amdgcn_s_setprio(0); \
    } while (0)
#define BAR() __builtin_amdgcn_s_barrier()
#define VM_FENCE(N) asm volatile("s_waitcnt vmcnt(" #N ")" ::: "memory")

    // prologue: tile0 full (buf0) + tile1 A-halves; ledger = 12 loads,
    // vmcnt(4) drains tile0's 8, leaves hA(t=1) x2 halves in flight
    STAGE_A(0, 0, 0);  STAGE_A(0, 128, 0);
    STAGE_B(0, 0, 0);  STAGE_B(0, 128, 0);
    STAGE_A(1, 0, 1);  STAGE_A(1, 128, 1);
    VM_FENCE(4);
    BAR();

    const int nIter = K >> 7;          // 2 K-tiles (2*64) per iteration
    for (int it = 0; it < nIter; it++) {
        const int t1 = 2 * it + 1, t2 = 2 * it + 2, t3 = 2 * it + 3;
        const bool full = (it < nIter - 1);
        // ---- phase 1: read tile0 A m0-3 + B n0-1; stage hB0(t1)
        RD_A(0, 0); RD_B(0, 0);
        STAGE_B(1, 0, t1);
        BAR(); MFMA_Q(0, 0); BAR();
        // ---- phase 2: read tile0 A m4-7 + B n2-3; stage hB1(t1)
        RD_A(0, 1); RD_B(0, 1);
        STAGE_B(1, 128, t1);
        BAR(); MFMA_Q(1, 0); BAR();
        // ---- phase 3: stage hA0(t2) (buf0 A reads all drained by ph2 MFMA)
        if (full) STAGE_A(0, 0, t2);
        BAR(); MFMA_Q(0, 1); BAR();
        // ---- phase 4: stage hA1(t2); counted drain -> tile t1 fully landed
        if (full) { STAGE_A(0, 128, t2); VM_FENCE(4); }
        else      { VM_FENCE(0); }
        BAR(); MFMA_Q(1, 1); BAR();
        // ---- phase 5: read tile1 A m0-3 + B n0-1; stage hB0(t2)
        RD_A(1, 0); RD_B(1, 0);
        if (full) STAGE_B(0, 0, t2);
        BAR(); MFMA_Q(0, 0); BAR();
        // ---- phase 6: read tile1 A m4-7 + B n2-3; stage hB1(t2)
        RD_A(1, 1); RD_B(1, 1);
        if (full) STAGE_B(0, 128, t2);
        BAR(); MFMA_Q(1, 0); BAR();
        // ---- phase 7: stage hA0(t3)
        if (full) STAGE_A(1, 0, t3);
        BAR(); MFMA_Q(0, 1); BAR();
        // ---- phase 8: stage hA1(t3); counted drain -> tile t2 fully landed
        if (full) { STAGE_A(1, 128, t3); VM_FENCE(4); }
        BAR(); MFMA_Q(1, 1); BAR();
    }

    // epilogue: C/D layout col=lane&15, row=(lane>>4)*4+i  [m89-verified]
    const int er = (lane >> 4) << 2;
    const int ec = lane & 15;
    u16* dsel = C0;
    const float* bsel = bias;
    if (EPI == 0) {
        int sub = col0 >> 9;
        dsel = (sub == 0) ? C0 : ((sub == 1) ? C1 : C2);
        bsel = (sub == 0) ? bias : ((sub == 1) ? auxb1 : auxb2);
    }
    #pragma unroll
    for (int mi = 0; mi < 8; mi++) {
        #pragma unroll
        for (int ni = 0; ni < 4; ni++) {
            #pragma unroll
            for (int i = 0; i < 4; i++) {
                int r  = row0 + (wm << 7) + (mi << 4) + er + i;
                int cc = col0 + (wn << 6) + (ni << 4) + ec;
                float v = acc[mi][ni][i];
                if (EPI == 0) {
                    int cl = cc & 511;
                    dsel[(size_t)r * 512 + cl] = f2b(v + bsel[cl]);
                } else if (EPI == 1) {
                    size_t o = (size_t)r * ldc + cc;
                    float bb2 = bias ? bias[cc] : 0.f;
                    C0[o] = f2b(b2f(C0[o]) + v + bb2);
                } else if (EPI == 2) {
                    size_t o = (size_t)r * ldc + cc;
                    float z = v + bias[cc];
                    C0[o] = f2b(0.5f * z * (1.f + erff(z * 0.7071067811865475f)));
                } else {
                    float vv = v * stdev[r];
                    atomicAdd(&fout[(((size_t)(r >> 5) * kT + cc) << 5) + (r & 31)], vv);
                }
            }
        }
    }
#undef STAGE_A
#undef STAGE_B
#undef RD_A
#undef RD_B
#undef MFMA_Q
#undef BAR
#undef VM_FENCE
}

// ---------------------------------------------------------------------------
// MFMA attention. One block per series; 4 waves; wave w does heads 2w, 2w+1.
// q,k,v: bf16 [rows=64*series][512]; output in place over q.
// ---------------------------------------------------------------------------
__global__ __launch_bounds__(256) void attn_mfma_kernel(
    u16* __restrict__ qbuf, const u16* __restrict__ kbuf,
    const u16* __restrict__ vbuf)
{
    __shared__ u16 P[4][64 * 64];   // 8 KB per wave
    const int tid = threadIdx.x;
    const int wave = tid >> 6, lane = tid & 63;
    const int quad = lane >> 4, l15 = lane & 15;
    const size_t base = (size_t)blockIdx.x * 64 * kD;
    u16* Pw = P[wave];

    for (int hh = 0; hh < 2; hh++) {
        const int h = wave * 2 + hh;
        const u16* qh = qbuf + base + h * 64;
        const u16* kh = kbuf + base + h * 64;
        const u16* vh = vbuf + base + h * 64;

        short8 af[4][2], bf[4][2];
        #pragma unroll
        for (int mi = 0; mi < 4; mi++)
            #pragma unroll
            for (int kt = 0; kt < 2; kt++)
                af[mi][kt] = *(const short8*)(qh + (size_t)(mi * 16 + l15) * kD
                                              + kt * 32 + quad * 8);
        #pragma unroll
        for (int ni = 0; ni < 4; ni++)
            #pragma unroll
            for (int kt = 0; kt < 2; kt++)
                bf[ni][kt] = *(const short8*)(kh + (size_t)(ni * 16 + l15) * kD
                                              + kt * 32 + quad * 8);
        f32x4 S[4][4];
        #pragma unroll
        for (int mi = 0; mi < 4; mi++)
            #pragma unroll
            for (int ni = 0; ni < 4; ni++)
                S[mi][ni] = (f32x4){0.f, 0.f, 0.f, 0.f};
        #pragma unroll
        for (int mi = 0; mi < 4; mi++)
            #pragma unroll
            for (int ni = 0; ni < 4; ni++) {
                S[mi][ni] = __builtin_amdgcn_mfma_f32_16x16x32_bf16(
                    af[mi][0], bf[ni][0], S[mi][ni], 0, 0, 0);
                S[mi][ni] = __builtin_amdgcn_mfma_f32_16x16x32_bf16(
                    af[mi][1], bf[ni][1], S[mi][ni], 0, 0, 0);
            }

        #pragma unroll
        for (int mi = 0; mi < 4; mi++) {
            #pragma unroll
            for (int i = 0; i < 4; i++) {
                float mx = -1e30f;
                #pragma unroll
                for (int ni = 0; ni < 4; ni++) {
                    float v = S[mi][ni][i] * 0.125f;
                    S[mi][ni][i] = v;
                    mx = fmaxf(mx, v);
                }
                #pragma unroll
                for (int off = 1; off < 16; off <<= 1)
                    mx = fmaxf(mx, __shfl_xor(mx, off));
                float sum = 0.f;
                #pragma unroll
                for (int ni = 0; ni < 4; ni++) {
                    float e = expf(S[mi][ni][i] - mx);
                    S[mi][ni][i] = e;
                    sum += e;
                }
                #pragma unroll
                for (int off = 1; off < 16; off <<= 1)
                    sum += __shfl_xor(sum, off);
                float inv = 1.f / sum;
                #pragma unroll
                for (int ni = 0; ni < 4; ni++)
                    Pw[(mi * 16 + quad * 4 + i) * 64 + ni * 16 + l15] =
                        f2b(S[mi][ni][i] * inv);
            }
        }
        __syncthreads();

        short8 bv[4][2];
        #pragma unroll
        for (int ni = 0; ni < 4; ni++)
            #pragma unroll
            for (int kt = 0; kt < 2; kt++)
                #pragma unroll
                for (int j = 0; j < 8; j++)
                    bv[ni][kt][j] = (short)vh[(size_t)(kt * 32 + quad * 8 + j) * kD
                                              + ni * 16 + l15];
        short8 pa[4][2];
        #pragma unroll
        for (int mi = 0; mi < 4; mi++)
            #pragma unroll
            for (int kt = 0; kt < 2; kt++)
                pa[mi][kt] = *(const short8*)&Pw[(mi * 16 + l15) * 64
                                                 + kt * 32 + quad * 8];
        f32x4 O[4][4];
        #pragma unroll
        for (int mi = 0; mi < 4; mi++)
            #pragma unroll
            for (int ni = 0; ni < 4; ni++)
                O[mi][ni] = (f32x4){0.f, 0.f, 0.f, 0.f};
        #pragma unroll
        for (int mi = 0; mi < 4; mi++)
            #pragma unroll
            for (int ni = 0; ni < 4; ni++) {
                O[mi][ni] = __builtin_amdgcn_mfma_f32_16x16x32_bf16(
                    pa[mi][0], bv[ni][0], O[mi][ni], 0, 0, 0);
                O[mi][ni] = __builtin_amdgcn_mfma_f32_16x16x32_bf16(
                    pa[mi][1], bv[ni][1], O[mi][ni], 0, 0, 0);
            }
        u16* qo = qbuf + base + h * 64;
        #pragma unroll
        for (int mi = 0; mi < 4; mi++)
            #pragma unroll
            for (int ni = 0; ni < 4; ni++)
                #pragma unroll
                for (int i = 0; i < 4; i++)
                    qo[(size_t)(mi * 16 + quad * 4 + i) * kD + ni * 16 + l15] =
                        f2b(O[mi][ni][i]);
        __syncthreads();
    }
}

// ---------------------------------------------------------------------------
// Row LayerNorm over D=512, bf16 in/out, in-place safe. 4 rows per block.
// ---------------------------------------------------------------------------
__global__ __launch_bounds__(256) void ln_kernel(
    const u16* __restrict__ x, const float* __restrict__ g,
    const float* __restrict__ bb, u16* __restrict__ y)
{
    size_t row = (size_t)blockIdx.x * 4 + (threadIdx.x >> 6);
    int lane = threadIdx.x & 63;
    float v[8];
    float s = 0.f;
    #pragma unroll
    for (int i = 0; i < 8; i++) {
        v[i] = b2f(x[row * kD + lane + i * 64]);
        s += v[i];
    }
    #pragma unroll
    for (int off = 32; off; off >>= 1) s += __shfl_xor(s, off);
    float mean = s * (1.f / kD);
    float sq = 0.f;
    #pragma unroll
    for (int i = 0; i < 8; i++) { float d = v[i] - mean; sq += d * d; }
    #pragma unroll
    for (int off = 32; off; off >>= 1) sq += __shfl_xor(sq, off);
    float inv = 1.f / sqrtf(sq * (1.f / kD) + 1e-5f);
    #pragma unroll
    for (int i = 0; i < 8; i++) {
        int d = lane + i * 64;
        y[row * kD + d] = f2b((v[i] - mean) * inv * g[d] + bb[d]);
    }
}

// ---------------------------------------------------------------------------
// BatchNorm pieces
// ---------------------------------------------------------------------------
__global__ void zero_kernel(float* __restrict__ p, int n)
{
    int i = blockIdx.x * blockDim.x + threadIdx.x;
    if (i < n) p[i] = 0.f;
}

__global__ __launch_bounds__(512) void bn_stats_kernel(
    const u16* __restrict__ tok, float* __restrict__ sums, float* __restrict__ sumsq)
{
    int d = threadIdx.x;
    float s = 0.f, sq = 0.f;
    int row0 = blockIdx.x * 256;
    for (int row = row0; row < row0 + 256; row++) {
        float v = b2f(tok[(size_t)row * kD + d]);
        s += v; sq += v * v;
    }
    atomicAdd(&sums[d], s);
    atomicAdd(&sumsq[d], sq);
}

__global__ __launch_bounds__(512) void bn_final_kernel(
    const float* __restrict__ sums, const float* __restrict__ sumsq,
    const float* __restrict__ g, const float* __restrict__ bb,
    float* __restrict__ scale, float* __restrict__ shift)
{
    int d = threadIdx.x;
    float mean = sums[d] / (float)kM;
    float var = sumsq[d] / (float)kM - mean * mean;
    float sc = g[d] / sqrtf(var + 1e-5f);
    scale[d] = sc;
    shift[d] = bb[d] - mean * sc;
}

// in-place BN on tok (bf16)
__global__ __launch_bounds__(256) void bn_apply_kernel(
    u16* __restrict__ tok, const float* __restrict__ scale,
    const float* __restrict__ shift)
{
    size_t i = (size_t)blockIdx.x * 256 + threadIdx.x;
    int d = (int)(i & 511);
    tok[i] = f2b(b2f(tok[i]) * scale[d] + shift[d]);
}

// out[(b*T+t)*C+c] = b_head[t]*stdev[r]+means[r]  (split-K partials add onto it)
__global__ __launch_bounds__(256) void head_init_kernel(
    float* __restrict__ out, const float* __restrict__ b_head,
    const float* __restrict__ stdev, const float* __restrict__ means)
{
    int i = blockIdx.x * 256 + threadIdx.x;
    int c = i & 31, t = (i >> 5) & 511, b = i >> 14;
    int r = b * 32 + c;
    out[i] = b_head[t] * stdev[r] + means[r];
}

// ---------------------------------------------------------------------------
// Launch
// ---------------------------------------------------------------------------
extern "C" void kernel_launch(void* const* d_in, const int* in_sizes, int n_in,
                              void* d_out, int out_size, void* d_ws, size_t ws_size,
                              hipStream_t stream)
{
    const float* x_enc  = (const float*)d_in[0];
    const float* W_val  = (const float*)d_in[1];
    const float* Wq     = (const float*)d_in[2];
    const float* bq     = (const float*)d_in[3];
    const float* Wk     = (const float*)d_in[4];
    const float* bk     = (const float*)d_in[5];
    const float* Wv     = (const float*)d_in[6];
    const float* bv     = (const float*)d_in[7];
    const float* Wo     = (const float*)d_in[8];
    const float* bo     = (const float*)d_in[9];
    const float* Wc1    = (const float*)d_in[10];
    const float* bc1    = (const float*)d_in[11];
    const float* Wc2    = (const float*)d_in[12];
    const float* bc2    = (const float*)d_in[13];
    const float* ln1_g  = (const float*)d_in[14];
    const float* ln1_b  = (const float*)d_in[15];
    const float* ln2_g  = (const float*)d_in[16];
    const float* ln2_b  = (const float*)d_in[17];
    const float* bn_g   = (const float*)d_in[18];
    const float* bn_b   = (const float*)d_in[19];
    const float* W_head = (const float*)d_in[20];
    const float* b_head = (const float*)d_in[21];
    float* out = (float*)d_out;

    // --- adaptive chunk size: largest CH with tok + 3 units + weights fitting
    const size_t tailBytes = (2 * kR + 4 * kD) * sizeof(float);
    const size_t headWb = (size_t)512 * 32768;   // W_head bf16 overlay elems
    int CH = 0; size_t unit = 0, region = 0;
    const int cands[4] = {1024, 512, 256, 128};
    for (int ci = 0; ci < 4; ci++) {
        size_t u = (size_t)cands[ci] * 64 * kD;
        size_t reg = 3 * u + kWbElems;
        if (reg < headWb) reg = headWb;
        size_t need = ((size_t)kM * kD + reg) * 2 + tailBytes;
        if (need <= ws_size) { CH = cands[ci]; unit = u; region = reg; break; }
    }
    if (CH == 0) {
        hipLaunchKernelGGL(fill_kernel, dim3((out_size + 255) / 256), dim3(256), 0,
                           stream, out, 1.0e6f, out_size);
        return;
    }
    const int nch = kR / CH;
    const int chRows = CH * 64;

    u16* tokb = (u16*)d_ws;
    u16* s0  = tokb + (size_t)kM * kD;
    u16* s1  = s0 + unit;
    u16* s2  = s1 + unit;
    u16* wbL = s2 + unit;
    u16* wbH = s0;
    u16* wQKV = wbL;                       // [1536][512]
    u16* wO   = wQKV + (size_t)1536 * 512; // [512][512]
    u16* wC1  = wO + (size_t)512 * 512;    // [2048][512]
    u16* wC2  = wC1 + (size_t)2048 * 512;  // [512][2048]
    float* tail = (float*)(s0 + region);
    float* means    = tail;
    float* stdevp   = means + kR;
    float* bn_sums  = stdevp + kR;
    float* bn_sumsq = bn_sums + kD;
    float* bn_scale = bn_sumsq + kD;
    float* bn_shift = bn_scale + kD;

    hipLaunchKernelGGL(instnorm_stats_kernel, dim3(kB), dim3(256), 0, stream,
                       x_enc, means, stdevp);
    hipLaunchKernelGGL(patch_embed_kernel, dim3(kM), dim3(256), 0, stream,
                       x_enc, W_val, means, stdevp, tokb);

    const dim3 blk(256);
    const dim3 blk512(512);
    const dim3 tr8(8, 8, 1);
    const int mt256 = chRows / 256;   // 256-row M tiles per chunk

    for (int i = 0; i < kNL; i++) {
        const float* Wq_i = Wq + (size_t)i * kD * kD;
        const float* Wk_i = Wk + (size_t)i * kD * kD;
        const float* Wv_i = Wv + (size_t)i * kD * kD;
        const float* Wo_i = Wo + (size_t)i * kD * kD;
        const float* Wc1_i = Wc1 + (size_t)i * kD * kDFF;
        const float* Wc2_i = Wc2 + (size_t)i * kDFF * kD;
        const float* bq_i = bq + i * kD, *bk_i = bk + i * kD, *bv_i = bv + i * kD;

        hipLaunchKernelGGL(transpose_cvt_kernel, tr8, blk, 0, stream,
                           Wq_i, wQKV, kD, kD, 0, 0);
        hipLaunchKernelGGL(transpose_cvt_kernel, tr8, blk, 0, stream,
                           Wk_i, wQKV + (size_t)512 * 512, kD, kD, 0, 0);
        hipLaunchKernelGGL(transpose_cvt_kernel, tr8, blk, 0, stream,
                           Wv_i, wQKV + (size_t)1024 * 512, kD, kD, 0, 0);
        hipLaunchKernelGGL(transpose_cvt_kernel, tr8, blk, 0, stream,
                           Wo_i, wO, kD, kD, 0, 0);
        hipLaunchKernelGGL(transpose_cvt_kernel, dim3(8, 32, 1), blk, 0, stream,
                           Wc1_i, wC1, kDFF, kD, 0, 0);
        hipLaunchKernelGGL(transpose_cvt_kernel, dim3(32, 8, 1), blk, 0, stream,
                           Wc2_i, wC2, kD, kDFF, 0, 0);

        for (int ch = 0; ch < nch; ch++) {
            u16* tokc = tokb + (size_t)ch * chRows * kD;
            // fused QKV: N=1536, routed to s0/s1/s2
            hipLaunchKernelGGL((gemm8<0>), dim3(6, mt256, 1), blk512, 0, stream,
                               tokc, wQKV, bq_i, bk_i, bv_i, s0, s1, s2,
                               nullptr, nullptr, kD, kD, kD, kD);
            hipLaunchKernelGGL(attn_mfma_kernel, dim3(CH), blk, 0, stream,
                               s0, s1, s2);
            // tok += attn_out @ Wo + bo
            hipLaunchKernelGGL((gemm8<1>), dim3(2, mt256, 1), blk512, 0, stream,
                               s0, wO, bo + i * kD, nullptr, nullptr,
                               tokc, nullptr, nullptr, nullptr, nullptr,
                               kD, kD, kD, kD);
            // y = LN1(tok) -> s0
            hipLaunchKernelGGL(ln_kernel, dim3(chRows / 4), blk, 0, stream,
                               tokc, ln1_g + i * kD, ln1_b + i * kD, s0);
            // FFN in two DFF/2 halves; h lives in s1:s2 (2 units)
            for (int half = 0; half < 2; half++) {
                const u16* wc1h = wC1 + (size_t)half * 1024 * 512;
                const u16* wc2h = wC2 + (size_t)half * 1024;   // k-offset
                const float* bc1h = bc1 + (size_t)i * kDFF + half * 1024;
                hipLaunchKernelGGL((gemm8<2>), dim3(4, mt256, 1), blk512, 0, stream,
                                   s0, wc1h, bc1h, nullptr, nullptr,
                                   s1, nullptr, nullptr, nullptr, nullptr,
                                   kD, kD, kD, 1024);
                hipLaunchKernelGGL((gemm8<1>), dim3(2, mt256, 1), blk512, 0, stream,
                                   s1, wc2h, (half == 0) ? (bc2 + i * kD) : nullptr,
                                   nullptr, nullptr, tokc, nullptr, nullptr,
                                   nullptr, nullptr, 1024, 1024, kDFF, kD);
            }
            // tok = LN2(tok) in place
            hipLaunchKernelGGL(ln_kernel, dim3(chRows / 4), blk, 0, stream,
                               tokc, ln2_g + i * kD, ln2_b + i * kD, tokc);
        }
    }

    // BatchNorm (stats -> apply in place on tok)
    hipLaunchKernelGGL(zero_kernel, dim3(1), dim3(1024), 0, stream, bn_sums, 2 * kD);
    hipLaunchKernelGGL(bn_stats_kernel, dim3(kM / 256), dim3(512), 0, stream,
                       tokb, bn_sums, bn_sumsq);
    hipLaunchKernelGGL(bn_final_kernel, dim3(1), dim3(512), 0, stream,
                       bn_sums, bn_sumsq, bn_g, bn_b, bn_scale, bn_shift);
    hipLaunchKernelGGL(bn_apply_kernel, dim3((int)((size_t)kM * kD / 256)), blk, 0,
                       stream, tokb, bn_scale, bn_shift);

    // head weights: wbH[t][n*512+d] = W_head[(d*64+n)*512+t]  (k' = n*512+d)
    hipLaunchKernelGGL(transpose_cvt_kernel, dim3(8, 8, 64), blk, 0, stream,
                       W_head, wbH, 64 * 512, 32768, 512, 512);
    // out = b_head*stdev+mean, then split-K MFMA adds acc*stdev
    hipLaunchKernelGGL(head_init_kernel, dim3(out_size / 256), blk, 0, stream,
                       out, b_head, stdevp, means);
    // A = tok viewed as [1024][32768] (k'=n*512+d is the flat tok order)
    // split-K z=32: K=1024 per slice, 256 blocks (1/CU, 8-phase pipeline hides)
    hipLaunchKernelGGL((gemm8<3>), dim3(2, 4, 32), blk512, 0, stream,
                       tokb, wbH, nullptr, nullptr, nullptr,
                       nullptr, nullptr, nullptr, out, stdevp,
                       1024, 32768, 32768, kT);
}

// Round 2
// 3235.467 us; speedup vs baseline: 1.1919x; 1.1568x over previous
//
#include <hip/hip_runtime.h>
#include <math.h>

// ---------------------------------------------------------------------------
// Problem constants (PatchTST-style transformer)
// ---------------------------------------------------------------------------
namespace {
constexpr int kB = 32, kT = 512, kC = 32, kD = 512, kDFF = 2048, kNL = 3;
constexpr int kP = 16, kStride = 8, kN = 64;
constexpr int kR = kB * kC;      // 1024 independent (b,c) series
constexpr int kM = kR * kN;      // 65536 tokens total
constexpr size_t kWbElems = (size_t)1536 * 512 + 512 * 512 + 2048 * 512 + 512 * 2048;
}

typedef unsigned short u16;
typedef __attribute__((ext_vector_type(8))) short short8;   // 8 bf16 (4 VGPRs)
typedef __attribute__((ext_vector_type(4))) float f32x4;    // MFMA accumulator
typedef __attribute__((address_space(3))) u16 lds_u16_t;

__device__ __forceinline__ float b2f(u16 u) {
    return __uint_as_float(((unsigned int)u) << 16);
}
__device__ __forceinline__ u16 f2b(float f) {
    unsigned int x = __float_as_uint(f);
    return (u16)((x + 0x7fffu + ((x >> 16) & 1u)) >> 16);
}

// Staging via raw inline asm so the compiler's waitcnt-insertion pass cannot
// see the pending LDS writes (with the builtin it conservatively emits
// s_waitcnt vmcnt(0) before every ds_read of the same LDS array, defeating
// the counted-vmcnt pipeline — R1 diagnosis: 3170 cy/phase, MfmaUtil 5%).
// lds_byte must be wave-uniform; HW writes lane*16 from it.  "memory"
// clobber pins program order of ds_reads vs stage issue; runtime ordering
// is enforced by the hand VM_FENCE + s_barrier ledger.
__device__ __forceinline__ void stage16(const u16* g, unsigned lds_byte) {
    unsigned m0v = (unsigned)__builtin_amdgcn_readfirstlane((int)lds_byte);
    asm volatile("s_mov_b32 m0, %0\n\t"
                 "global_load_lds_dwordx4 %1, off"
                 :: "s"(m0v), "v"(g) : "memory");
}

// ---------------------------------------------------------------------------
// Sentinel fill (workspace-too-small diagnostic)
// ---------------------------------------------------------------------------
__global__ void fill_kernel(float* __restrict__ p, float val, int n)
{
    int i = blockIdx.x * blockDim.x + threadIdx.x;
    if (i < n) p[i] = val;
}

// ---------------------------------------------------------------------------
// Instance-norm stats per (b,c)
// ---------------------------------------------------------------------------
__global__ __launch_bounds__(256) void instnorm_stats_kernel(
    const float* __restrict__ x, float* __restrict__ means, float* __restrict__ stdev)
{
    int b = blockIdx.x;
    int c = threadIdx.x & 31;
    int g = threadIdx.x >> 5;
    float s = 0.f, sq = 0.f;
    for (int t = g; t < kT; t += 8) {
        float v = x[(size_t)(b * kT + t) * kC + c];
        s += v; sq += v * v;
    }
    __shared__ float ss[8][32], ssq[8][32];
    ss[g][c] = s; ssq[g][c] = sq;
    __syncthreads();
    if (g == 0) {
        float S = 0.f, SQ = 0.f;
        for (int i = 0; i < 8; i++) { S += ss[i][c]; SQ += ssq[i][c]; }
        float m = S / kT;
        float var = SQ / kT - m * m;
        means[b * kC + c] = m;
        stdev[b * kC + c] = sqrtf(var + 1e-5f);
    }
}

// ---------------------------------------------------------------------------
// Patch embed (bf16 out)
// ---------------------------------------------------------------------------
__global__ __launch_bounds__(256) void patch_embed_kernel(
    const float* __restrict__ x, const float* __restrict__ Wval,
    const float* __restrict__ means, const float* __restrict__ stdev,
    u16* __restrict__ tok)
{
    int m = blockIdx.x;
    int r = m >> 6, n = m & 63;
    int b = r >> 5, c = r & 31;
    __shared__ float patch[kP];
    if (threadIdx.x < kP) {
        int t = n * kStride + threadIdx.x;
        if (t > kT - 1) t = kT - 1;
        patch[threadIdx.x] = (x[(size_t)(b * kT + t) * kC + c] - means[r]) / stdev[r];
    }
    __syncthreads();
    for (int d = threadIdx.x; d < kD; d += 256) {
        float acc = 0.f;
        #pragma unroll
        for (int p = 0; p < kP; p++) acc += patch[p] * Wval[p * kD + d];
        int j = d >> 1;
        float freq = expf(-(float)(2 * j) * (9.210340371976184f / (float)kD));
        float ang = (float)n * freq;
        float pe = (d & 1) ? cosf(ang) : sinf(ang);
        tok[(size_t)m * kD + d] = f2b(acc + pe);
    }
}

// ---------------------------------------------------------------------------
// Transpose + fp32->bf16 convert: out[n*ldo + k] = f2b(in[k*ldi + n])
// per z-slice: in += z*zin, out += z*zout.  grid (K/64, N/64, Z), 256 thr.
// ---------------------------------------------------------------------------
__global__ __launch_bounds__(256) void transpose_cvt_kernel(
    const float* __restrict__ in, u16* __restrict__ outp,
    int ldi, int ldo, int zin, int zout)
{
    __shared__ float tile[64][65];
    const float* ib = in + (size_t)blockIdx.z * zin;
    u16* ob = outp + (size_t)blockIdx.z * zout;
    int k0 = blockIdx.x * 64, n0 = blockIdx.y * 64;
    int tn = threadIdx.x & 63, tk0 = threadIdx.x >> 6;
    #pragma unroll
    for (int kk = tk0; kk < 64; kk += 4)
        tile[kk][tn] = ib[(size_t)(k0 + kk) * ldi + n0 + tn];
    __syncthreads();
    int wk = threadIdx.x & 63, wn0 = threadIdx.x >> 6;
    #pragma unroll
    for (int nn = wn0; nn < 64; nn += 4)
        ob[(size_t)(n0 + nn) * ldo + k0 + wk] = f2b(tile[wk][nn]);
}

// ---------------------------------------------------------------------------
// 256x256-tile, BK=64, 8-wave, 8-phase MFMA bf16 GEMM (T2+T3+T4+T5+T1).
//
// A: [M][lda] bf16 row-major.  B: [N][ldb] bf16 N-MAJOR (row n = output col).
// grid: (N/256, M/256, Z).  Z>1 = split-K (global k = z*K + kb), EPI 3 only.
// 512 threads = 8 waves (2M x 4N); per-wave output 128x64; acc[8][4] f32x4.
//
// LDS 128 KiB: {A0,B0,A1,B1} x 16K u16, linear [row][64] with chunk-XOR
// swizzle: 16B phys chunk p of row r holds logical chunk p ^ (r&7)
// (2-way max bank aliasing on ds_read_b128 -> free; global src pre-swizzled
// since global_load_lds writes base+lane*16 linearly).
//
// Schedule (race-free ledger):
//   tile t -> buf[t&1]; iteration it computes tiles t0=2it (buf0, phases 1-4,
//   frags read ph1-2, reg-resident for ph3-4) and t1=2it+1 (buf1, phases 5-8).
//   Stage map: ph1 hB0(t1) ph2 hB1(t1) ph3 hA0(t2) ph4 hA1(t2)
//              ph5 hB0(t2) ph6 hB1(t2) ph7 hA0(t3) ph8 hA1(t3)
//   vmcnt(4) at ph4/ph8 drains exactly the next tile's 4 halves while leaving
//   2 half-tiles (4 loads) in flight.  Final iteration: no ph3-8 stages,
//   vmcnt(0) at ph4.
// EPI 0: qkv — dst/bias by 512-col group: C0/C1/C2, bias/auxb1/auxb2
// EPI 1: C0[r*ldc+c] += acc + (bias?bias[c]:0)       (bf16 rmw)
// EPI 2: C0[r*ldc+c]  = gelu_erf(acc + bias[c])
// EPI 3: atomicAdd(fout[((r>>5)*512+c)*32 + (r&31)], acc*stdev[r])
// ---------------------------------------------------------------------------
template<int EPI>
__global__ __launch_bounds__(512, 2) void gemm8(
    const u16* __restrict__ A, const u16* __restrict__ B,
    const float* __restrict__ bias, const float* __restrict__ auxb1,
    const float* __restrict__ auxb2,
    u16* __restrict__ C0, u16* __restrict__ C1, u16* __restrict__ C2,
    float* __restrict__ fout, const float* __restrict__ stdev,
    int K, int lda, int ldb, int ldc)
{
    __shared__ u16 sm[65536];          // 128 KiB
    u16* const bufA0 = sm;
    u16* const bufB0 = sm + 16384;
    u16* const bufA1 = sm + 32768;
    u16* const bufB1 = sm + 49152;

    // absolute LDS byte addresses for the asm staging path (M0 value)
    const unsigned smBase = (unsigned)(size_t)(lds_u16_t*)(void*)sm;
    const unsigned ldsA0 = smBase;
    const unsigned ldsB0 = smBase + 16384u * 2u;
    const unsigned ldsA1 = smBase + 32768u * 2u;
    const unsigned ldsB1 = smBase + 49152u * 2u;

    const int tid  = threadIdx.x;
    const int lane = tid & 63;
    const int wave = tid >> 6;
    const int wm   = wave >> 2;        // 0..1
    const int wn   = wave & 3;         // 0..3

    // bijective XCD swizzle (m204) over the (x,y) grid plane
    const int nwg  = gridDim.x * gridDim.y;
    const int orig = blockIdx.y * gridDim.x + blockIdx.x;
    const int qq = nwg >> 3, rr = nwg & 7;
    const int xcd = orig & 7, loc = orig >> 3;
    const int wg  = (xcd < rr) ? (xcd * (qq + 1) + loc)
                               : (rr * (qq + 1) + (xcd - rr) * qq + loc);
    const int row0 = (wg / gridDim.x) * 256;
    const int col0 = (wg % gridDim.x) * 256;
    const size_t zoff = (size_t)blockIdx.z * K;

    // staging: one global_load_lds covers 64 rows (512 thr x 16B); the lane
    // fetches logical chunk (lane&7)^(lane>>3) so linear LDS ends up swizzled
    const int srow = (wave << 3) + (lane >> 3);          // 0..63
    const int scol = ((lane & 7) ^ (lane >> 3)) << 3;
    const u16* const Ag = A + (size_t)(row0 + srow) * lda + zoff + scol;
    const u16* const Bg = B + (size_t)(col0 + srow) * ldb + zoff + scol;
    const int lw = wave << 3;

#define STAGE_A(BUF, R0, T) do { \
        const u16* g_ = Ag + (size_t)(R0) * lda + (T) * 64; \
        unsigned l_ = ldsA##BUF + (unsigned)(((R0) + lw) << 7); \
        stage16(g_, l_); \
        stage16(g_ + (size_t)64 * lda, l_ + 8192u); \
    } while (0)
#define STAGE_B(BUF, R0, T) do { \
        const u16* g_ = Bg + (size_t)(R0) * ldb + (T) * 64; \
        unsigned l_ = ldsB##BUF + (unsigned)(((R0) + lw) << 7); \
        stage16(g_, l_); \
        stage16(g_ + (size_t)64 * ldb, l_ + 8192u); \
    } while (0)

    // fragment read offsets (u16 elements); phys chunk for kt=0 is
    // quad^(row&7) with row&7 == lane&7; kt=1 flips bit2 of the phys chunk
    const int fr = lane & 15;
    const int pc = (lane >> 4) ^ (lane & 7);
    const int a0 = ((wm << 7) + fr) * 64 + pc * 8;
    const int a1 = ((wm << 7) + fr) * 64 + (pc ^ 4) * 8;
    const int b0 = ((wn << 6) + fr) * 64 + pc * 8;
    const int b1 = ((wn << 6) + fr) * 64 + (pc ^ 4) * 8;

    short8 af[8][2], bfr[4][2];
    f32x4 acc[8][4];
    #pragma unroll
    for (int i = 0; i < 8; i++)
        #pragma unroll
        for (int j = 0; j < 4; j++)
            acc[i][j] = (f32x4){0.f, 0.f, 0.f, 0.f};

#define RD_A(BUF, MH) do { \
        _Pragma("unroll") \
        for (int mi_ = 0; mi_ < 4; mi_++) { \
            af[(MH)*4 + mi_][0] = *(const short8*)&bufA##BUF[a0 + (((MH)*4 + mi_) << 10)]; \
            af[(MH)*4 + mi_][1] = *(const short8*)&bufA##BUF[a1 + (((MH)*4 + mi_) << 10)]; \
        } \
    } while (0)
#define RD_B(BUF, NH) do { \
        _Pragma("unroll") \
        for (int ni_ = 0; ni_ < 2; ni_++) { \
            bfr[(NH)*2 + ni_][0] = *(const short8*)&bufB##BUF[b0 + (((NH)*2 + ni_) << 10)]; \
            bfr[(NH)*2 + ni_][1] = *(const short8*)&bufB##BUF[b1 + (((NH)*2 + ni_) << 10)]; \
        } \
    } while (0)
#define MFMA_Q(MH, NH) do { \
        __builtin_amdgcn_s_setprio(1); \
        _Pragma("unroll") \
        for (int mi_ = 0; mi_ < 4; mi_++) \
            _Pragma("unroll") \
            for (int ni_ = 0; ni_ < 2; ni_++) { \
                acc[(MH)*4 + mi_][(NH)*2 + ni_] = __builtin_amdgcn_mfma_f32_16x16x32_bf16( \
                    af[(MH)*4 + mi_][0], bfr[(NH)*2 + ni_][0], \
                    acc[(MH)*4 + mi_][(NH)*2 + ni_], 0, 0, 0); \
                acc[(MH)*4 + mi_][(NH)*2 + ni_] = __builtin_amdgcn_mfma_f32_16x16x32_bf16( \
                    af[(MH)*4 + mi_][1], bfr[(NH)*2 + ni_][1], \
                    acc[(MH)*4 + mi_][(NH)*2 + ni_], 0, 0, 0); \
            } \
        __builtin_amdgcn_s_setprio(0); \
    } while (0)
#define BAR() __builtin_amdgcn_s_barrier()
#define VM_FENCE(N) asm volatile("s_waitcnt vmcnt(" #N ")" ::: "memory")

    // prologue: tile0 full (buf0) + tile1 A-halves; ledger = 12 loads,
    // vmcnt(4) drains tile0's 8, leaves hA(t=1) x2 halves in flight
    STAGE_A(0, 0, 0);  STAGE_A(0, 128, 0);
    STAGE_B(0, 0, 0);  STAGE_B(0, 128, 0);
    STAGE_A(1, 0, 1);  STAGE_A(1, 128, 1);
    VM_FENCE(4);
    BAR();

    const int nIter = K >> 7;          // 2 K-tiles (2*64) per iteration
    for (int it = 0; it < nIter; it++) {
        const int t1 = 2 * it + 1, t2 = 2 * it + 2, t3 = 2 * it + 3;
        const bool full = (it < nIter - 1);
        // ---- phase 1: read tile0 A m0-3 + B n0-1; stage hB0(t1)
        RD_A(0, 0); RD_B(0, 0);
        STAGE_B(1, 0, t1);
        BAR(); MFMA_Q(0, 0); BAR();
        // ---- phase 2: read tile0 A m4-7 + B n2-3; stage hB1(t1)
        RD_A(0, 1); RD_B(0, 1);
        STAGE_B(1, 128, t1);
        BAR(); MFMA_Q(1, 0); BAR();
        // ---- phase 3: stage hA0(t2) (buf0 A reads all drained by ph2 MFMA)
        if (full) STAGE_A(0, 0, t2);
        BAR(); MFMA_Q(0, 1); BAR();
        // ---- phase 4: stage hA1(t2); counted drain -> tile t1 fully landed
        if (full) { STAGE_A(0, 128, t2); VM_FENCE(4); }
        else      { VM_FENCE(0); }
        BAR(); MFMA_Q(1, 1); BAR();
        // ---- phase 5: read tile1 A m0-3 + B n0-1; stage hB0(t2)
        RD_A(1, 0); RD_B(1, 0);
        if (full) STAGE_B(0, 0, t2);
        BAR(); MFMA_Q(0, 0); BAR();
        // ---- phase 6: read tile1 A m4-7 + B n2-3; stage hB1(t2)
        RD_A(1, 1); RD_B(1, 1);
        if (full) STAGE_B(0, 128, t2);
        BAR(); MFMA_Q(1, 0); BAR();
        // ---- phase 7: stage hA0(t3)
        if (full) STAGE_A(1, 0, t3);
        BAR(); MFMA_Q(0, 1); BAR();
        // ---- phase 8: stage hA1(t3); counted drain -> tile t2 fully landed
        if (full) { STAGE_A(1, 128, t3); VM_FENCE(4); }
        BAR(); MFMA_Q(1, 1); BAR();
    }

    // epilogue: C/D layout col=lane&15, row=(lane>>4)*4+i  [m89-verified]
    const int er = (lane >> 4) << 2;
    const int ec = lane & 15;
    u16* dsel = C0;
    const float* bsel = bias;
    if (EPI == 0) {
        int sub = col0 >> 9;
        dsel = (sub == 0) ? C0 : ((sub == 1) ? C1 : C2);
        bsel = (sub == 0) ? bias : ((sub == 1) ? auxb1 : auxb2);
    }
    #pragma unroll
    for (int mi = 0; mi < 8; mi++) {
        #pragma unroll
        for (int ni = 0; ni < 4; ni++) {
            #pragma unroll
            for (int i = 0; i < 4; i++) {
                int r  = row0 + (wm << 7) + (mi << 4) + er + i;
                int cc = col0 + (wn << 6) + (ni << 4) + ec;
                float v = acc[mi][ni][i];
                if (EPI == 0) {
                    int cl = cc & 511;
                    dsel[(size_t)r * 512 + cl] = f2b(v + bsel[cl]);
                } else if (EPI == 1) {
                    size_t o = (size_t)r * ldc + cc;
                    float bb2 = bias ? bias[cc] : 0.f;
                    C0[o] = f2b(b2f(C0[o]) + v + bb2);
                } else if (EPI == 2) {
                    size_t o = (size_t)r * ldc + cc;
                    float z = v + bias[cc];
                    C0[o] = f2b(0.5f * z * (1.f + erff(z * 0.7071067811865475f)));
                } else {
                    float vv = v * stdev[r];
                    atomicAdd(&fout[(((size_t)(r >> 5) * kT + cc) << 5) + (r & 31)], vv);
                }
            }
        }
    }
#undef STAGE_A
#undef STAGE_B
#undef RD_A
#undef RD_B
#undef MFMA_Q
#undef BAR
#undef VM_FENCE
}

// ---------------------------------------------------------------------------
// MFMA attention. One block per series; 4 waves; wave w does heads 2w, 2w+1.
// q,k,v: bf16 [rows=64*series][512]; output in place over q.
// ---------------------------------------------------------------------------
__global__ __launch_bounds__(256) void attn_mfma_kernel(
    u16* __restrict__ qbuf, const u16* __restrict__ kbuf,
    const u16* __restrict__ vbuf)
{
    __shared__ u16 P[4][64 * 64];   // 8 KB per wave
    const int tid = threadIdx.x;
    const int wave = tid >> 6, lane = tid & 63;
    const int quad = lane >> 4, l15 = lane & 15;
    const size_t base = (size_t)blockIdx.x * 64 * kD;
    u16* Pw = P[wave];

    for (int hh = 0; hh < 2; hh++) {
        const int h = wave * 2 + hh;
        const u16* qh = qbuf + base + h * 64;
        const u16* kh = kbuf + base + h * 64;
        const u16* vh = vbuf + base + h * 64;

        short8 af[4][2], bf[4][2];
        #pragma unroll
        for (int mi = 0; mi < 4; mi++)
            #pragma unroll
            for (int kt = 0; kt < 2; kt++)
                af[mi][kt] = *(const short8*)(qh + (size_t)(mi * 16 + l15) * kD
                                              + kt * 32 + quad * 8);
        #pragma unroll
        for (int ni = 0; ni < 4; ni++)
            #pragma unroll
            for (int kt = 0; kt < 2; kt++)
                bf[ni][kt] = *(const short8*)(kh + (size_t)(ni * 16 + l15) * kD
                                              + kt * 32 + quad * 8);
        f32x4 S[4][4];
        #pragma unroll
        for (int mi = 0; mi < 4; mi++)
            #pragma unroll
            for (int ni = 0; ni < 4; ni++)
                S[mi][ni] = (f32x4){0.f, 0.f, 0.f, 0.f};
        #pragma unroll
        for (int mi = 0; mi < 4; mi++)
            #pragma unroll
            for (int ni = 0; ni < 4; ni++) {
                S[mi][ni] = __builtin_amdgcn_mfma_f32_16x16x32_bf16(
                    af[mi][0], bf[ni][0], S[mi][ni], 0, 0, 0);
                S[mi][ni] = __builtin_amdgcn_mfma_f32_16x16x32_bf16(
                    af[mi][1], bf[ni][1], S[mi][ni], 0, 0, 0);
            }

        #pragma unroll
        for (int mi = 0; mi < 4; mi++) {
            #pragma unroll
            for (int i = 0; i < 4; i++) {
                float mx = -1e30f;
                #pragma unroll
                for (int ni = 0; ni < 4; ni++) {
                    float v = S[mi][ni][i] * 0.125f;
                    S[mi][ni][i] = v;
                    mx = fmaxf(mx, v);
                }
                #pragma unroll
                for (int off = 1; off < 16; off <<= 1)
                    mx = fmaxf(mx, __shfl_xor(mx, off));
                float sum = 0.f;
                #pragma unroll
                for (int ni = 0; ni < 4; ni++) {
                    float e = expf(S[mi][ni][i] - mx);
                    S[mi][ni][i] = e;
                    sum += e;
                }
                #pragma unroll
                for (int off = 1; off < 16; off <<= 1)
                    sum += __shfl_xor(sum, off);
                float inv = 1.f / sum;
                #pragma unroll
                for (int ni = 0; ni < 4; ni++)
                    Pw[(mi * 16 + quad * 4 + i) * 64 + ni * 16 + l15] =
                        f2b(S[mi][ni][i] * inv);
            }
        }
        __syncthreads();

        short8 bv[4][2];
        #pragma unroll
        for (int ni = 0; ni < 4; ni++)
            #pragma unroll
            for (int kt = 0; kt < 2; kt++)
                #pragma unroll
                for (int j = 0; j < 8; j++)
                    bv[ni][kt][j] = (short)vh[(size_t)(kt * 32 + quad * 8 + j) * kD
                                              + ni * 16 + l15];
        short8 pa[4][2];
        #pragma unroll
        for (int mi = 0; mi < 4; mi++)
            #pragma unroll
            for (int kt = 0; kt < 2; kt++)
                pa[mi][kt] = *(const short8*)&Pw[(mi * 16 + l15) * 64
                                                 + kt * 32 + quad * 8];
        f32x4 O[4][4];
        #pragma unroll
        for (int mi = 0; mi < 4; mi++)
            #pragma unroll
            for (int ni = 0; ni < 4; ni++)
                O[mi][ni] = (f32x4){0.f, 0.f, 0.f, 0.f};
        #pragma unroll
        for (int mi = 0; mi < 4; mi++)
            #pragma unroll
            for (int ni = 0; ni < 4; ni++) {
                O[mi][ni] = __builtin_amdgcn_mfma_f32_16x16x32_bf16(
                    pa[mi][0], bv[ni][0], O[mi][ni], 0, 0, 0);
                O[mi][ni] = __builtin_amdgcn_mfma_f32_16x16x32_bf16(
                    pa[mi][1], bv[ni][1], O[mi][ni], 0, 0, 0);
            }
        u16* qo = qbuf + base + h * 64;
        #pragma unroll
        for (int mi = 0; mi < 4; mi++)
            #pragma unroll
            for (int ni = 0; ni < 4; ni++)
                #pragma unroll
                for (int i = 0; i < 4; i++)
                    qo[(size_t)(mi * 16 + quad * 4 + i) * kD + ni * 16 + l15] =
                        f2b(O[mi][ni][i]);
        __syncthreads();
    }
}

// ---------------------------------------------------------------------------
// Row LayerNorm over D=512, bf16 in/out, in-place safe. 4 rows per block.
// ---------------------------------------------------------------------------
__global__ __launch_bounds__(256) void ln_kernel(
    const u16* __restrict__ x, const float* __restrict__ g,
    const float* __restrict__ bb, u16* __restrict__ y)
{
    size_t row = (size_t)blockIdx.x * 4 + (threadIdx.x >> 6);
    int lane = threadIdx.x & 63;
    float v[8];
    float s = 0.f;
    #pragma unroll
    for (int i = 0; i < 8; i++) {
        v[i] = b2f(x[row * kD + lane + i * 64]);
        s += v[i];
    }
    #pragma unroll
    for (int off = 32; off; off >>= 1) s += __shfl_xor(s, off);
    float mean = s * (1.f / kD);
    float sq = 0.f;
    #pragma unroll
    for (int i = 0; i < 8; i++) { float d = v[i] - mean; sq += d * d; }
    #pragma unroll
    for (int off = 32; off; off >>= 1) sq += __shfl_xor(sq, off);
    float inv = 1.f / sqrtf(sq * (1.f / kD) + 1e-5f);
    #pragma unroll
    for (int i = 0; i < 8; i++) {
        int d = lane + i * 64;
        y[row * kD + d] = f2b((v[i] - mean) * inv * g[d] + bb[d]);
    }
}

// ---------------------------------------------------------------------------
// BatchNorm pieces
// ---------------------------------------------------------------------------
__global__ void zero_kernel(float* __restrict__ p, int n)
{
    int i = blockIdx.x * blockDim.x + threadIdx.x;
    if (i < n) p[i] = 0.f;
}

__global__ __launch_bounds__(512) void bn_stats_kernel(
    const u16* __restrict__ tok, float* __restrict__ sums, float* __restrict__ sumsq)
{
    int d = threadIdx.x;
    float s = 0.f, sq = 0.f;
    int row0 = blockIdx.x * 256;
    for (int row = row0; row < row0 + 256; row++) {
        float v = b2f(tok[(size_t)row * kD + d]);
        s += v; sq += v * v;
    }
    atomicAdd(&sums[d], s);
    atomicAdd(&sumsq[d], sq);
}

__global__ __launch_bounds__(512) void bn_final_kernel(
    const float* __restrict__ sums, const float* __restrict__ sumsq,
    const float* __restrict__ g, const float* __restrict__ bb,
    float* __restrict__ scale, float* __restrict__ shift)
{
    int d = threadIdx.x;
    float mean = sums[d] / (float)kM;
    float var = sumsq[d] / (float)kM - mean * mean;
    float sc = g[d] / sqrtf(var + 1e-5f);
    scale[d] = sc;
    shift[d] = bb[d] - mean * sc;
}

// in-place BN on tok (bf16)
__global__ __launch_bounds__(256) void bn_apply_kernel(
    u16* __restrict__ tok, const float* __restrict__ scale,
    const float* __restrict__ shift)
{
    size_t i = (size_t)blockIdx.x * 256 + threadIdx.x;
    int d = (int)(i & 511);
    tok[i] = f2b(b2f(tok[i]) * scale[d] + shift[d]);
}

// out[(b*T+t)*C+c] = b_head[t]*stdev[r]+means[r]  (split-K partials add onto it)
__global__ __launch_bounds__(256) void head_init_kernel(
    float* __restrict__ out, const float* __restrict__ b_head,
    const float* __restrict__ stdev, const float* __restrict__ means)
{
    int i = blockIdx.x * 256 + threadIdx.x;
    int c = i & 31, t = (i >> 5) & 511, b = i >> 14;
    int r = b * 32 + c;
    out[i] = b_head[t] * stdev[r] + means[r];
}

// ---------------------------------------------------------------------------
// Launch
// ---------------------------------------------------------------------------
extern "C" void kernel_launch(void* const* d_in, const int* in_sizes, int n_in,
                              void* d_out, int out_size, void* d_ws, size_t ws_size,
                              hipStream_t stream)
{
    const float* x_enc  = (const float*)d_in[0];
    const float* W_val  = (const float*)d_in[1];
    const float* Wq     = (const float*)d_in[2];
    const float* bq     = (const float*)d_in[3];
    const float* Wk     = (const float*)d_in[4];
    const float* bk     = (const float*)d_in[5];
    const float* Wv     = (const float*)d_in[6];
    const float* bv     = (const float*)d_in[7];
    const float* Wo     = (const float*)d_in[8];
    const float* bo     = (const float*)d_in[9];
    const float* Wc1    = (const float*)d_in[10];
    const float* bc1    = (const float*)d_in[11];
    const float* Wc2    = (const float*)d_in[12];
    const float* bc2    = (const float*)d_in[13];
    const float* ln1_g  = (const float*)d_in[14];
    const float* ln1_b  = (const float*)d_in[15];
    const float* ln2_g  = (const float*)d_in[16];
    const float* ln2_b  = (const float*)d_in[17];
    const float* bn_g   = (const float*)d_in[18];
    const float* bn_b   = (const float*)d_in[19];
    const float* W_head = (const float*)d_in[20];
    const float* b_head = (const float*)d_in[21];
    float* out = (float*)d_out;

    // --- adaptive chunk size: largest CH with tok + 3 units + weights fitting
    const size_t tailBytes = (2 * kR + 4 * kD) * sizeof(float);
    const size_t headWb = (size_t)512 * 32768;   // W_head bf16 overlay elems
    int CH = 0; size_t unit = 0, region = 0;
    const int cands[4] = {1024, 512, 256, 128};
    for (int ci = 0; ci < 4; ci++) {
        size_t u = (size_t)cands[ci] * 64 * kD;
        size_t reg = 3 * u + kWbElems;
        if (reg < headWb) reg = headWb;
        size_t need = ((size_t)kM * kD + reg) * 2 + tailBytes;
        if (need <= ws_size) { CH = cands[ci]; unit = u; region = reg; break; }
    }
    if (CH == 0) {
        hipLaunchKernelGGL(fill_kernel, dim3((out_size + 255) / 256), dim3(256), 0,
                           stream, out, 1.0e6f, out_size);
        return;
    }
    const int nch = kR / CH;
    const int chRows = CH * 64;

    u16* tokb = (u16*)d_ws;
    u16* s0  = tokb + (size_t)kM * kD;
    u16* s1  = s0 + unit;
    u16* s2  = s1 + unit;
    u16* wbL = s2 + unit;
    u16* wbH = s0;
    u16* wQKV = wbL;                       // [1536][512]
    u16* wO   = wQKV + (size_t)1536 * 512; // [512][512]
    u16* wC1  = wO + (size_t)512 * 512;    // [2048][512]
    u16* wC2  = wC1 + (size_t)2048 * 512;  // [512][2048]
    float* tail = (float*)(s0 + region);
    float* means    = tail;
    float* stdevp   = means + kR;
    float* bn_sums  = stdevp + kR;
    float* bn_sumsq = bn_sums + kD;
    float* bn_scale = bn_sumsq + kD;
    float* bn_shift = bn_scale + kD;

    hipLaunchKernelGGL(instnorm_stats_kernel, dim3(kB), dim3(256), 0, stream,
                       x_enc, means, stdevp);
    hipLaunchKernelGGL(patch_embed_kernel, dim3(kM), dim3(256), 0, stream,
                       x_enc, W_val, means, stdevp, tokb);

    const dim3 blk(256);
    const dim3 blk512(512);
    const dim3 tr8(8, 8, 1);
    const int mt256 = chRows / 256;   // 256-row M tiles per chunk

    for (int i = 0; i < kNL; i++) {
        const float* Wq_i = Wq + (size_t)i * kD * kD;
        const float* Wk_i = Wk + (size_t)i * kD * kD;
        const float* Wv_i = Wv + (size_t)i * kD * kD;
        const float* Wo_i = Wo + (size_t)i * kD * kD;
        const float* Wc1_i = Wc1 + (size_t)i * kD * kDFF;
        const float* Wc2_i = Wc2 + (size_t)i * kDFF * kD;
        const float* bq_i = bq + i * kD, *bk_i = bk + i * kD, *bv_i = bv + i * kD;

        hipLaunchKernelGGL(transpose_cvt_kernel, tr8, blk, 0, stream,
                           Wq_i, wQKV, kD, kD, 0, 0);
        hipLaunchKernelGGL(transpose_cvt_kernel, tr8, blk, 0, stream,
                           Wk_i, wQKV + (size_t)512 * 512, kD, kD, 0, 0);
        hipLaunchKernelGGL(transpose_cvt_kernel, tr8, blk, 0, stream,
                           Wv_i, wQKV + (size_t)1024 * 512, kD, kD, 0, 0);
        hipLaunchKernelGGL(transpose_cvt_kernel, tr8, blk, 0, stream,
                           Wo_i, wO, kD, kD, 0, 0);
        hipLaunchKernelGGL(transpose_cvt_kernel, dim3(8, 32, 1), blk, 0, stream,
                           Wc1_i, wC1, kDFF, kD, 0, 0);
        hipLaunchKernelGGL(transpose_cvt_kernel, dim3(32, 8, 1), blk, 0, stream,
                           Wc2_i, wC2, kD, kDFF, 0, 0);

        for (int ch = 0; ch < nch; ch++) {
            u16* tokc = tokb + (size_t)ch * chRows * kD;
            // fused QKV: N=1536, routed to s0/s1/s2
            hipLaunchKernelGGL((gemm8<0>), dim3(6, mt256, 1), blk512, 0, stream,
                               tokc, wQKV, bq_i, bk_i, bv_i, s0, s1, s2,
                               nullptr, nullptr, kD, kD, kD, kD);
            hipLaunchKernelGGL(attn_mfma_kernel, dim3(CH), blk, 0, stream,
                               s0, s1, s2);
            // tok += attn_out @ Wo + bo
            hipLaunchKernelGGL((gemm8<1>), dim3(2, mt256, 1), blk512, 0, stream,
                               s0, wO, bo + i * kD, nullptr, nullptr,
                               tokc, nullptr, nullptr, nullptr, nullptr,
                               kD, kD, kD, kD);
            // y = LN1(tok) -> s0
            hipLaunchKernelGGL(ln_kernel, dim3(chRows / 4), blk, 0, stream,
                               tokc, ln1_g + i * kD, ln1_b + i * kD, s0);
            // FFN in two DFF/2 halves; h lives in s1:s2 (2 units)
            for (int half = 0; half < 2; half++) {
                const u16* wc1h = wC1 + (size_t)half * 1024 * 512;
                const u16* wc2h = wC2 + (size_t)half * 1024;   // k-offset
                const float* bc1h = bc1 + (size_t)i * kDFF + half * 1024;
                hipLaunchKernelGGL((gemm8<2>), dim3(4, mt256, 1), blk512, 0, stream,
                                   s0, wc1h, bc1h, nullptr, nullptr,
                                   s1, nullptr, nullptr, nullptr, nullptr,
                                   kD, kD, kD, 1024);
                hipLaunchKernelGGL((gemm8<1>), dim3(2, mt256, 1), blk512, 0, stream,
                                   s1, wc2h, (half == 0) ? (bc2 + i * kD) : nullptr,
                                   nullptr, nullptr, tokc, nullptr, nullptr,
                                   nullptr, nullptr, 1024, 1024, kDFF, kD);
            }
            // tok = LN2(tok) in place
            hipLaunchKernelGGL(ln_kernel, dim3(chRows / 4), blk, 0, stream,
                               tokc, ln2_g + i * kD, ln2_b + i * kD, tokc);
        }
    }

    // BatchNorm (stats -> apply in place on tok)
    hipLaunchKernelGGL(zero_kernel, dim3(1), dim3(1024), 0, stream, bn_sums, 2 * kD);
    hipLaunchKernelGGL(bn_stats_kernel, dim3(kM / 256), dim3(512), 0, stream,
                       tokb, bn_sums, bn_sumsq);
    hipLaunchKernelGGL(bn_final_kernel, dim3(1), dim3(512), 0, stream,
                       bn_sums, bn_sumsq, bn_g, bn_b, bn_scale, bn_shift);
    hipLaunchKernelGGL(bn_apply_kernel, dim3((int)((size_t)kM * kD / 256)), blk, 0,
                       stream, tokb, bn_scale, bn_shift);

    // head weights: wbH[t][n*512+d] = W_head[(d*64+n)*512+t]  (k' = n*512+d)
    hipLaunchKernelGGL(transpose_cvt_kernel, dim3(8, 8, 64), blk, 0, stream,
                       W_head, wbH, 64 * 512, 32768, 512, 512);
    // out = b_head*stdev+mean, then split-K MFMA adds acc*stdev
    hipLaunchKernelGGL(head_init_kernel, dim3(out_size / 256), blk, 0, stream,
                       out, b_head, stdevp, means);
    // A = tok viewed as [1024][32768] (k'=n*512+d is the flat tok order)
    // split-K z=32: K=1024 per slice, 256 blocks (1/CU, 8-phase pipeline hides)
    hipLaunchKernelGGL((gemm8<3>), dim3(2, 4, 32), blk512, 0, stream,
                       tokb, wbH, nullptr, nullptr, nullptr,
                       nullptr, nullptr, nullptr, out, stdevp,
                       1024, 32768, 32768, kT);
}